// Round 9
// baseline (31.836 us; speedup 1.0000x reference)
//
#include <hip/hip_runtime.h>
#include <math.h>

#define EPSF    1e-6f
#define B_N     4096
#define P_N     128
#define D_N     128
#define NPAIRS  (P_N * (P_N - 1) / 2)   // 8128 = 127 * 64
#define ITERS   10
#define MAXNORM 0.99999f                 // (1 - 1e-5) / sqrt(c), c = 1
#define MCAP    512                      // max members per group handled
#define WCAP    128                      // per-wave member list capacity
#define SLOTS   64                       // staged slots (16 per wave, wave-owned)
#define SENT    0x5AFE1234               // ready sentinel (!= 0, != 0xAAAAAAAA)
#define BFIN    127                      // finalizer block (owns zero pairs)

// ---------------------------------------------------------------------------
// DPP helpers
// ---------------------------------------------------------------------------
template <int CTRL>
__device__ __forceinline__ float dppadd(float x) {
    float t = __int_as_float(__builtin_amdgcn_update_dpp(
        0, __float_as_int(x), CTRL, 0xf, 0xf, true));
    return x + t;
}
__device__ __forceinline__ float red8(float x) {       // sum over aligned 8 lanes
    x = dppadd<0xB1>(x);    // quad_perm xor 1
    x = dppadd<0x4E>(x);    // quad_perm xor 2
    x = dppadd<0x141>(x);   // row_half_mirror: xor 7
    return x;
}
__device__ __forceinline__ float red4(float x) {       // sum over aligned 4 lanes
    x = dppadd<0xB1>(x);
    x = dppadd<0x4E>(x);
    return x;
}
__device__ __forceinline__ float wsum64(float x) {
    x = dppadd<0x111>(x); x = dppadd<0x112>(x); x = dppadd<0x114>(x);
    x = dppadd<0x118>(x); x = dppadd<0x142>(x); x = dppadd<0x143>(x);
    return __int_as_float(__builtin_amdgcn_readlane(__float_as_int(x), 63));
}
__device__ __forceinline__ void wsum64_2(float& a, float& b) {
#define DPP_STEP(ctrl) \
    a = dppadd<ctrl>(a); b = dppadd<ctrl>(b);
    DPP_STEP(0x111) DPP_STEP(0x112) DPP_STEP(0x114) DPP_STEP(0x118) DPP_STEP(0x142) DPP_STEP(0x143)
#undef DPP_STEP
    a = __int_as_float(__builtin_amdgcn_readlane(__float_as_int(a), 63));
    b = __int_as_float(__builtin_amdgcn_readlane(__float_as_int(b), 63));
}
__device__ __forceinline__ double wred64d(double v) {
    v += __shfl_xor(v, 1);  v += __shfl_xor(v, 2);  v += __shfl_xor(v, 4);
    v += __shfl_xor(v, 8);  v += __shfl_xor(v, 16); v += __shfl_xor(v, 32);
    return v;
}
__device__ __forceinline__ float dot16(const float4* r, const float4* m) {
    float d = 0.f;
#pragma unroll
    for (int j = 0; j < 4; ++j)
        d += r[j].x * m[j].x + r[j].y * m[j].y + r[j].z * m[j].z + r[j].w * m[j].w;
    return d;
}

// ---------------------------------------------------------------------------
// ONE kernel: proto (R8 structure) -> publish mu -> flag sync -> dist (quad
// per pair, direct L2 reads) -> gpart publish -> block 127 finalizes corr.
// Flags use sentinel values (poison/stale-proof; stale is benign since the
// computation is bitwise deterministic across replays).
// ---------------------------------------------------------------------------
__global__ __launch_bounds__(256) void cpcc_kernel(
        const float* __restrict__ reps,
        const int*   __restrict__ targets,
        const int*   __restrict__ dT,
        float*  __restrict__ mu_out,
        float*  __restrict__ mu2_out,
        double* __restrict__ gpart,
        int*    __restrict__ muflag,
        int*    __restrict__ dflag,
        float*  __restrict__ out) {
    __shared__ int    wtmp[4][WCAP];
    __shared__ int    wcnt[4];
    __shared__ int    woff[4];
    __shared__ int    mlist[MCAP];
    __shared__ int    s_n;
    __shared__ float4 xs4[SLOTS * 32];   // 32 KiB; row m, f4-col c at [m*32 + (c^(m&7))]
    __shared__ float  sc_l[MCAP];
    __shared__ float  x2_l[MCAP];
    __shared__ float  w_l[MCAP];
    __shared__ float  cb_l[MCAP];
    __shared__ float  mu_lds[D_N];
    __shared__ float  part[2][4][D_N];
    __shared__ float  scbp[2][4];
    __shared__ double shd[4][3];         // dist partials per wave
    __shared__ double shtd[4][2];        // dT partials (block 127)

    const int p    = blockIdx.x;
    const int tid  = threadIdx.x;
    const int wv   = tid >> 6;
    const int lane = tid & 63;
    const int grp  = lane >> 3;
    const int q    = lane & 7;

    // ================= PROTO (identical math to R8) =================
    {
        int tg[16];
#pragma unroll
        for (int r = 0; r < 16; ++r) tg[r] = targets[(wv << 10) + (r << 6) + lane];
        const unsigned long long lowmask = (1ULL << lane) - 1ULL;
        int cnt = 0;
#pragma unroll
        for (int r = 0; r < 16; ++r) {
            bool mm = (tg[r] == p);
            unsigned long long mk = __ballot(mm);
            if (mm) {
                int pos = cnt + __popcll(mk & lowmask);
                if (pos < WCAP) wtmp[wv][pos] = (wv << 10) + (r << 6) + lane;
            }
            cnt += __popcll(mk);
        }
        if (cnt > WCAP) cnt = WCAP;
        if (lane == 0) wcnt[wv] = cnt;
    }
    __syncthreads();
    if (tid == 0) {
        int c0 = wcnt[0], c1 = wcnt[1], c2 = wcnt[2], c3 = wcnt[3];
        woff[0] = 0; woff[1] = c0; woff[2] = c0 + c1; woff[3] = c0 + c1 + c2;
        int nn = c0 + c1 + c2 + c3;
        s_n = (nn > MCAP) ? MCAP : nn;
    }
    __syncthreads();
    {
        int base = woff[wv], cnt = wcnt[wv];
        for (int i = lane; i < cnt; i += 64) mlist[base + i] = wtmp[wv][i];
    }
    __syncthreads();

    const int   n       = s_n;
    const float inv_cnt = 1.0f / fmaxf((float)n, 1.0f);
    const float4* reps4 = (const float4*)reps;
    const float2* reps2 = (const float2*)reps;

    const int mA = wv * 16 + grp;
    const int mB = mA + 8;

    float4 rA[4], rB[4];
    {
        bool act = (mA < n);
        int  b   = act ? mlist[mA] : 0;
        float ss = 0.f;
#pragma unroll
        for (int j = 0; j < 4; ++j) {
            rA[j] = reps4[(size_t)b * 32 + 4 * q + j];
            ss += rA[j].x * rA[j].x + rA[j].y * rA[j].y + rA[j].z * rA[j].z + rA[j].w * rA[j].w;
        }
        ss = red8(ss);
        float nn = fmaxf(sqrtf(ss), EPSF);
        float sv = act ? (tanhf(nn) / nn) : 0.f;
#pragma unroll
        for (int j = 0; j < 4; ++j) {
            rA[j].x *= sv; rA[j].y *= sv; rA[j].z *= sv; rA[j].w *= sv;
            xs4[mA * 32 + ((4 * q + j) ^ (mA & 7))] = rA[j];
        }
        if (q == 0) { sc_l[mA] = sv; x2_l[mA] = act ? ss * sv * sv : 0.f; }
    }
    {
        bool act = (mB < n);
        int  b   = act ? mlist[mB] : 0;
        float ss = 0.f;
#pragma unroll
        for (int j = 0; j < 4; ++j) {
            rB[j] = reps4[(size_t)b * 32 + 4 * q + j];
            ss += rB[j].x * rB[j].x + rB[j].y * rB[j].y + rB[j].z * rB[j].z + rB[j].w * rB[j].w;
        }
        ss = red8(ss);
        float nn = fmaxf(sqrtf(ss), EPSF);
        float sv = act ? (tanhf(nn) / nn) : 0.f;
#pragma unroll
        for (int j = 0; j < 4; ++j) {
            rB[j].x *= sv; rB[j].y *= sv; rB[j].z *= sv; rB[j].w *= sv;
            xs4[mB * 32 + ((4 * q + j) ^ (mB & 7))] = rB[j];
        }
        if (q == 0) { sc_l[mB] = sv; x2_l[mB] = act ? ss * sv * sv : 0.f; }
    }
    for (int mb = SLOTS + wv * 16; mb < n; mb += 64) {
#pragma unroll
        for (int t = 0; t < 2; ++t) {
            int  m   = mb + grp + 8 * t;
            bool act = (m < n);
            int  b   = act ? mlist[m] : 0;
            float ss = 0.f;
#pragma unroll
            for (int j = 0; j < 4; ++j) {
                float4 t4 = reps4[(size_t)b * 32 + 4 * q + j];
                ss += t4.x * t4.x + t4.y * t4.y + t4.z * t4.z + t4.w * t4.w;
            }
            ss = red8(ss);
            if (act && q == 0) {
                float nn = fmaxf(sqrtf(ss), EPSF);
                float sv = tanhf(nn) / nn;
                sc_l[m] = sv;
                x2_l[m] = ss * sv * sv;
            }
        }
    }

    const float* xsf = (const float*)xs4;
    const int    lh  = lane >> 1, lb = (lane & 1) * 2;

    {
        float2 S; S.x = 0.f; S.y = 0.f;
#pragma unroll
        for (int k = 0; k < 16; ++k) {
            int m = wv * 16 + k;
            float2 xv = *(const float2*)&xsf[(m * 32 + (lh ^ (m & 7))) * 4 + lb];
            S.x += xv.x; S.y += xv.y;
        }
        for (int mb = SLOTS + wv * 16; mb < n; mb += 64) {
            for (int k = 0; k < 16; ++k) {
                int m = mb + k;
                if (m < n) {
                    float2 rv = reps2[(size_t)mlist[m] * 64 + lane];
                    float s = sc_l[m];
                    S.x += s * rv.x; S.y += s * rv.y;
                }
            }
        }
        *(float2*)&part[1][wv][2 * lane] = S;
    }
    __syncthreads();
    float2 muf; float mu2;
    {
        float2 T; T.x = 0.f; T.y = 0.f;
#pragma unroll
        for (int w2 = 0; w2 < 4; ++w2) {
            float2 pv = *(const float2*)&part[1][w2][2 * lane];
            T.x += pv.x; T.y += pv.y;
        }
        muf.x = T.x * inv_cnt; muf.y = T.y * inv_cnt;
        float m2  = wsum64(muf.x * muf.x + muf.y * muf.y);
        float nrm = fmaxf(sqrtf(m2), EPSF);
        float fac = fminf(1.0f, MAXNORM / nrm);
        muf.x *= fac; muf.y *= fac;
        mu2 = m2 * fac * fac;
        *(float2*)&mu_lds[2 * lane] = muf;
    }

    for (int it = 0; it < ITERS; ++it) {
        const int buf = it & 1;
        const float4* mu4 = (const float4*)mu_lds;
        float4 ms[4];
#pragma unroll
        for (int j = 0; j < 4; ++j) ms[j] = mu4[4 * q + j];

        {
            float d   = red8(dot16(rA, ms));
            float x2v = x2_l[mA];
            float ca  = 1.0f - 2.0f * d + mu2;
            float cbv = 1.0f - x2v;
            float den = fmaxf(1.0f - 2.0f * d + x2v * mu2, EPSF);
            float iv  = 1.0f / den;
            bool  act = (mA < n);
            if (q == 0) { w_l[mA] = act ? ca * iv : 0.f; cb_l[mA] = act ? cbv * iv : 0.f; }
        }
        {
            float d   = red8(dot16(rB, ms));
            float x2v = x2_l[mB];
            float ca  = 1.0f - 2.0f * d + mu2;
            float cbv = 1.0f - x2v;
            float den = fmaxf(1.0f - 2.0f * d + x2v * mu2, EPSF);
            float iv  = 1.0f / den;
            bool  act = (mB < n);
            if (q == 0) { w_l[mB] = act ? ca * iv : 0.f; cb_l[mB] = act ? cbv * iv : 0.f; }
        }
        for (int mb = SLOTS + wv * 16; mb < n; mb += 64) {
#pragma unroll
            for (int t = 0; t < 2; ++t) {
                int  m   = mb + grp + 8 * t;
                bool act = (m < n);
                int  b   = act ? mlist[m] : 0;
                float dd = 0.f;
#pragma unroll
                for (int j = 0; j < 4; ++j) {
                    float4 a = reps4[(size_t)b * 32 + 4 * q + j];
                    dd += a.x * ms[j].x + a.y * ms[j].y + a.z * ms[j].z + a.w * ms[j].w;
                }
                dd = red8(dd);
                if (act) {
                    float dp  = sc_l[m] * dd;
                    float x2v = x2_l[m];
                    float ca  = 1.0f - 2.0f * dp + mu2;
                    float cbv = 1.0f - x2v;
                    float den = fmaxf(1.0f - 2.0f * dp + x2v * mu2, EPSF);
                    float iv  = 1.0f / den;
                    if (q == 0) { w_l[m] = ca * iv; cb_l[m] = cbv * iv; }
                }
            }
        }

        float2 S2; S2.x = 0.f; S2.y = 0.f;
        float  scb = 0.f;
#pragma unroll
        for (int k = 0; k < 16; ++k) {
            int m = wv * 16 + k;
            float wvv = w_l[m];
            scb += cb_l[m];
            float2 xv = *(const float2*)&xsf[(m * 32 + (lh ^ (m & 7))) * 4 + lb];
            S2.x += wvv * xv.x; S2.y += wvv * xv.y;
        }
        for (int mb = SLOTS + wv * 16; mb < n; mb += 64) {
            for (int k = 0; k < 16; ++k) {
                int m = mb + k;
                if (m < n) {
                    float wvv = w_l[m] * sc_l[m];
                    scb += cb_l[m];
                    float2 rv = reps2[(size_t)mlist[m] * 64 + lane];
                    S2.x += wvv * rv.x; S2.y += wvv * rv.y;
                }
            }
        }
        *(float2*)&part[buf][wv][2 * lane] = S2;
        if (lane == 0) scbp[buf][wv] = scb;
        __syncthreads();

        float2 T; T.x = 0.f; T.y = 0.f;
#pragma unroll
        for (int w2 = 0; w2 < 4; ++w2) {
            float2 pv = *(const float2*)&part[buf][w2][2 * lane];
            T.x += pv.x; T.y += pv.y;
        }
        float scbt = scbp[buf][0] + scbp[buf][1] + scbp[buf][2] + scbp[buf][3];
        float scs  = scbt * inv_cnt;
        float2 md;
        md.x = T.x * inv_cnt - scs * muf.x;
        md.y = T.y * inv_cnt - scs * muf.y;

        float A0 = md.x * md.x + md.y * md.y;
        float A1 = muf.x * md.x + muf.y * md.y;
        wsum64_2(A0, A1);
        float ca  = 1.0f + 2.0f * A1 + A0;
        float cbv = 1.0f - mu2;
        float den = fmaxf(1.0f + 2.0f * A1 + mu2 * A0, EPSF);
        float iv  = 1.0f / den;
        float2 tv;
        tv.x = (ca * muf.x + cbv * md.x) * iv;
        tv.y = (ca * muf.y + cbv * md.y) * iv;
        float t2   = (ca * ca * mu2 + 2.0f * ca * cbv * A1 + cbv * cbv * A0) * iv * iv;
        float nrm2 = fmaxf(sqrtf(t2), EPSF);
        float fc   = fminf(1.0f, MAXNORM / nrm2);
        muf.x = tv.x * fc; muf.y = tv.y * fc;
        mu2   = t2 * fc * fc;
        *(float2*)&mu_lds[2 * lane] = muf;
    }

    {
        float nf = fmaxf(sqrtf(mu2), EPSF);
        float ff = fminf(1.0f, MAXNORM / nf);
        muf.x *= ff; muf.y *= ff;
        mu2 = mu2 * ff * ff;
    }
    // ---- publish mu (wave 0 stores; tid0's fence covers wave-0 vmcnt)
    if (wv == 0) {
        ((float2*)(mu_out + (size_t)p * D_N))[lane] = muf;
        if (lane == 0) mu2_out[p] = mu2;
    }
    if (tid == 0) {
        __threadfence();   // release: L2 writeback to coherence point
        __hip_atomic_store(&muflag[p], SENT, __ATOMIC_RELAXED, __HIP_MEMORY_SCOPE_AGENT);
    }

    // ---- block 127: overlap dT sums with other blocks' protos
    if (p == BFIN) {
        double st = 0.0, st2 = 0.0;
        for (int k2 = tid; k2 < NPAIRS; k2 += 256) {
            double tt = (double)dT[k2];
            st += tt; st2 += tt * tt;
        }
        st  = wred64d(st);
        st2 = wred64d(st2);
        if (lane == 0) { shtd[wv][0] = st; shtd[wv][1] = st2; }
    }

    // ---- wait for all protos (wave 0 lane-parallel spin)
    if (tid < 64) {
        for (;;) {
            int a = __hip_atomic_load(&muflag[lane],      __ATOMIC_RELAXED, __HIP_MEMORY_SCOPE_AGENT);
            int c = __hip_atomic_load(&muflag[lane + 64], __ATOMIC_RELAXED, __HIP_MEMORY_SCOPE_AGENT);
            if (__all((a == SENT) && (c == SENT))) break;
            __builtin_amdgcn_s_sleep(2);
        }
    }
    __syncthreads();
    __builtin_amdgcn_fence(__ATOMIC_ACQUIRE, "agent");   // invalidate stale lines

    // ================= DIST: quad per pair, direct L2 reads =================
    double p0 = 0.0, p1 = 0.0, p4 = 0.0;
    if (p < BFIN) {
        int kk = p * 64 + (tid >> 2);        // all valid: 127*64 == NPAIRS
        int qd = tid & 3;
        int i = (int)(127.5f - sqrtf(127.5f * 127.5f - 2.0f * (float)kk));
        if (i < 0) i = 0;
        while ((i + 1) * (2 * P_N - i - 2) / 2 <= kk) ++i;
        while (i * (2 * P_N - i - 1) / 2 > kk) --i;
        int j = kk - i * (2 * P_N - i - 1) / 2 + i + 1;

        const float4* ra = (const float4*)(mu_out + (size_t)i * D_N) + qd * 8;
        const float4* rb = (const float4*)(mu_out + (size_t)j * D_N) + qd * 8;
        float acc = 0.f;
#pragma unroll
        for (int d = 0; d < 8; ++d) {
            float4 a = ra[d], b = rb[d];
            float f0 = a.x - b.x, f1 = a.y - b.y, f2 = a.z - b.z, f3 = a.w - b.w;
            acc += f0 * f0 + f1 * f1 + f2 * f2 + f3 * f3;
        }
        acc = red4(acc);                     // quad sum
        if (qd == 0) {
            float ai = fmaxf(1.f - mu2_out[i], EPSF);
            float aj = fmaxf(1.f - mu2_out[j], EPSF);
            float z  = 1.f + 2.f * acc / fmaxf(ai * aj, EPSF);
            z = fmaxf(z, 1.f + EPSF);
            float dist = acoshf(z);
            double bb = (double)dist;
            double tt = (double)dT[kk];
            p0 = bb; p1 = bb * bb; p4 = bb * tt;
        }
    }
    p0 = wred64d(p0); p1 = wred64d(p1); p4 = wred64d(p4);
    if (lane == 0) { shd[wv][0] = p0; shd[wv][1] = p1; shd[wv][2] = p4; }
    __syncthreads();
    if (tid == 0 && p < BFIN) {
        double b0 = shd[0][0] + shd[1][0] + shd[2][0] + shd[3][0];
        double b1 = shd[0][1] + shd[1][1] + shd[2][1] + shd[3][1];
        double b4 = shd[0][2] + shd[1][2] + shd[2][2] + shd[3][2];
        gpart[p * 3 + 0] = b0;
        gpart[p * 3 + 1] = b1;
        gpart[p * 3 + 2] = b4;
        __threadfence();
        __hip_atomic_store(&dflag[p], SENT, __ATOMIC_RELAXED, __HIP_MEMORY_SCOPE_AGENT);
    }

    // ================= FINALIZE (block 127) =================
    if (p == BFIN) {
        if (tid < 64) {
            for (;;) {
                int a = SENT, c = SENT;
                a = __hip_atomic_load(&dflag[lane], __ATOMIC_RELAXED, __HIP_MEMORY_SCOPE_AGENT);
                if (lane + 64 < BFIN)
                    c = __hip_atomic_load(&dflag[lane + 64], __ATOMIC_RELAXED, __HIP_MEMORY_SCOPE_AGENT);
                if (__all((a == SENT) && (c == SENT))) break;
                __builtin_amdgcn_s_sleep(2);
            }
        }
        __syncthreads();
        __builtin_amdgcn_fence(__ATOMIC_ACQUIRE, "agent");
        if (tid < 64) {
            double q0 = 0.0, q1 = 0.0, q2 = 0.0;
            for (int b = lane; b < BFIN; b += 64) {
                q0 += gpart[b * 3 + 0];
                q1 += gpart[b * 3 + 1];
                q2 += gpart[b * 3 + 2];
            }
            q0 = wred64d(q0); q1 = wred64d(q1); q2 = wred64d(q2);
            if (tid == 0) {
                double st  = shtd[0][0] + shtd[1][0] + shtd[2][0] + shtd[3][0];
                double st2 = shtd[0][1] + shtd[1][1] + shtd[2][1] + shtd[3][1];
                const double nn = (double)NPAIRS;
                double mb  = q0 / nn;
                double mt  = st / nn;
                double cov = q2 - nn * mb * mt;
                double vb  = q1 - nn * mb * mb;
                double vt  = st2 - nn * mt * mt;
                double corr = cov / sqrt(vb * vt);
                double res  = isnan(corr) ? 1.0 : (1.0 - corr);
                out[0] = (float)res;
            }
        }
    }
}

// ---------------------------------------------------------------------------
extern "C" void kernel_launch(void* const* d_in, const int* in_sizes, int n_in,
                              void* d_out, int out_size, void* d_ws, size_t ws_size,
                              hipStream_t stream) {
    const float* reps    = (const float*)d_in[0];
    const int*   targets = (const int*)d_in[1];
    const int*   dT      = (const int*)d_in[2];
    float* out = (float*)d_out;

    float*  mu     = (float*)d_ws;                        // 65536 B
    float*  mu2s   = (float*)((char*)d_ws + 65536);       // 512 B
    double* gpart  = (double*)((char*)d_ws + 66048);      // 127*3*8 B
    int*    muflag = (int*)((char*)d_ws + 69632);         // 512 B
    int*    dflag  = (int*)((char*)d_ws + 70144);         // 512 B

    cpcc_kernel<<<P_N, 256, 0, stream>>>(reps, targets, dT, mu, mu2s,
                                         gpart, muflag, dflag, out);
}

// Round 10
// 28.042 us; speedup vs baseline: 1.1353x; 1.1353x over previous
//
#include <hip/hip_runtime.h>
#include <math.h>

#define EPSF    1e-6f
#define B_N     4096
#define P_N     128
#define D_N     128
#define NPAIRS  (P_N * (P_N - 1) / 2)   // 8128
#define ITERS   10
#define MAXNORM 0.99999f                 // (1 - 1e-5) / sqrt(c), c = 1
#define MCAP    512                      // max members per group handled
#define WCAP    128                      // per-wave member list capacity
#define SLOTS   64                       // staged slots (16 per wave, wave-owned)

// ---------------------------------------------------------------------------
// DPP / lane helpers
// ---------------------------------------------------------------------------
template <int CTRL>
__device__ __forceinline__ float dppadd(float x) {
    float t = __int_as_float(__builtin_amdgcn_update_dpp(
        0, __float_as_int(x), CTRL, 0xf, 0xf, true));
    return x + t;
}
__device__ __forceinline__ float red8(float x) {       // sum over aligned 8 lanes
    x = dppadd<0xB1>(x);    // quad_perm xor 1
    x = dppadd<0x4E>(x);    // quad_perm xor 2
    x = dppadd<0x141>(x);   // row_half_mirror: xor 7
    return x;
}
__device__ __forceinline__ float wsum64(float x) {
    x = dppadd<0x111>(x); x = dppadd<0x112>(x); x = dppadd<0x114>(x);
    x = dppadd<0x118>(x); x = dppadd<0x142>(x); x = dppadd<0x143>(x);
    return __int_as_float(__builtin_amdgcn_readlane(__float_as_int(x), 63));
}
__device__ __forceinline__ void wsum64_2(float& a, float& b) {
#define DPP_STEP(ctrl) \
    a = dppadd<ctrl>(a); b = dppadd<ctrl>(b);
    DPP_STEP(0x111) DPP_STEP(0x112) DPP_STEP(0x114) DPP_STEP(0x118) DPP_STEP(0x142) DPP_STEP(0x143)
#undef DPP_STEP
    a = __int_as_float(__builtin_amdgcn_readlane(__float_as_int(a), 63));
    b = __int_as_float(__builtin_amdgcn_readlane(__float_as_int(b), 63));
}
__device__ __forceinline__ double wred64d(double v) {
    v += __shfl_xor(v, 1);  v += __shfl_xor(v, 2);  v += __shfl_xor(v, 4);
    v += __shfl_xor(v, 8);  v += __shfl_xor(v, 16); v += __shfl_xor(v, 32);
    return v;
}
__device__ __forceinline__ float rlane(float v, int l) {   // l must fold to const
    return __int_as_float(__builtin_amdgcn_readlane(__float_as_int(v), l));
}
__device__ __forceinline__ float dot16(const float4* r, const float4* m) {
    float d = 0.f;
#pragma unroll
    for (int j = 0; j < 4; ++j)
        d += r[j].x * m[j].x + r[j].y * m[j].y + r[j].z * m[j].z + r[j].w * m[j].w;
    return d;
}
__device__ __forceinline__ float tanh_fast(float x) {      // x >= 0
    float t = __expf(-2.0f * x);
    return (1.0f - t) / (1.0f + t);
}

// ---------------------------------------------------------------------------
// Kernel 1: per-group Karcher mean. R8 structure (4 waves, wave-owned slots,
// 1 barrier/iter) + register-resident xd[16] (no per-iter LDS row reads) +
// readlane weight broadcast (no per-iter scalar LDS reads).
// ---------------------------------------------------------------------------
__global__ __launch_bounds__(256) void proto_kernel(
        const float* __restrict__ reps,
        const int*   __restrict__ targets,
        float* __restrict__ mu_out,
        float* __restrict__ mu2_out,
        int*   __restrict__ counter) {
    __shared__ int    wtmp[4][WCAP];
    __shared__ int    wcnt[4];
    __shared__ int    woff[4];
    __shared__ int    mlist[MCAP];
    __shared__ int    s_n;
    __shared__ float4 xs4[SLOTS * 32];   // 32 KiB; row m, f4-col c at [m*32 + (c^(m&7))]
    __shared__ float  sc_l[MCAP];        // fallback slots only
    __shared__ float  x2_l[MCAP];
    __shared__ float  w_l[MCAP];
    __shared__ float  cb_l[MCAP];
    __shared__ float  mu_lds[D_N];
    __shared__ float  part[2][4][D_N];
    __shared__ float  scbp[2][4];

    const int p    = blockIdx.x;
    const int tid  = threadIdx.x;
    const int wv   = tid >> 6;
    const int lane = tid & 63;
    const int grp  = lane >> 3;
    const int q    = lane & 7;

    if (p == 0 && tid == 0) counter[0] = 0;

    // ---- membership scan
    {
        int tg[16];
#pragma unroll
        for (int r = 0; r < 16; ++r) tg[r] = targets[(wv << 10) + (r << 6) + lane];
        const unsigned long long lowmask = (1ULL << lane) - 1ULL;
        int cnt = 0;
#pragma unroll
        for (int r = 0; r < 16; ++r) {
            bool mm = (tg[r] == p);
            unsigned long long mk = __ballot(mm);
            if (mm) {
                int pos = cnt + __popcll(mk & lowmask);
                if (pos < WCAP) wtmp[wv][pos] = (wv << 10) + (r << 6) + lane;
            }
            cnt += __popcll(mk);
        }
        if (cnt > WCAP) cnt = WCAP;
        if (lane == 0) wcnt[wv] = cnt;
    }
    __syncthreads();
    if (tid == 0) {
        int c0 = wcnt[0], c1 = wcnt[1], c2 = wcnt[2], c3 = wcnt[3];
        woff[0] = 0; woff[1] = c0; woff[2] = c0 + c1; woff[3] = c0 + c1 + c2;
        int nn = c0 + c1 + c2 + c3;
        s_n = (nn > MCAP) ? MCAP : nn;
    }
    __syncthreads();
    {
        int base = woff[wv], cnt = wcnt[wv];
        for (int i = lane; i < cnt; i += 64) mlist[base + i] = wtmp[wv][i];
    }
    __syncthreads();

    const int   n       = s_n;
    const float inv_cnt = 1.0f / fmaxf((float)n, 1.0f);
    const float4* reps4 = (const float4*)reps;
    const float2* reps2 = (const float2*)reps;

    const int mA = wv * 16 + grp;
    const int mB = mA + 8;

    // ---- stage own slots (expmap fused); keep x2 in registers
    float4 rA[4], rB[4];
    float  x2A, x2B;
    {
        bool act = (mA < n);
        int  b   = act ? mlist[mA] : 0;
        float ss = 0.f;
#pragma unroll
        for (int j = 0; j < 4; ++j) {
            rA[j] = reps4[(size_t)b * 32 + 4 * q + j];
            ss += rA[j].x * rA[j].x + rA[j].y * rA[j].y + rA[j].z * rA[j].z + rA[j].w * rA[j].w;
        }
        ss = red8(ss);
        float nn = fmaxf(sqrtf(ss), EPSF);
        float sv = act ? (tanh_fast(nn) / nn) : 0.f;
#pragma unroll
        for (int j = 0; j < 4; ++j) {
            rA[j].x *= sv; rA[j].y *= sv; rA[j].z *= sv; rA[j].w *= sv;
            xs4[mA * 32 + ((4 * q + j) ^ (mA & 7))] = rA[j];
        }
        x2A = act ? ss * sv * sv : 0.f;
    }
    {
        bool act = (mB < n);
        int  b   = act ? mlist[mB] : 0;
        float ss = 0.f;
#pragma unroll
        for (int j = 0; j < 4; ++j) {
            rB[j] = reps4[(size_t)b * 32 + 4 * q + j];
            ss += rB[j].x * rB[j].x + rB[j].y * rB[j].y + rB[j].z * rB[j].z + rB[j].w * rB[j].w;
        }
        ss = red8(ss);
        float nn = fmaxf(sqrtf(ss), EPSF);
        float sv = act ? (tanh_fast(nn) / nn) : 0.f;
#pragma unroll
        for (int j = 0; j < 4; ++j) {
            rB[j].x *= sv; rB[j].y *= sv; rB[j].z *= sv; rB[j].w *= sv;
            xs4[mB * 32 + ((4 * q + j) ^ (mB & 7))] = rB[j];
        }
        x2B = act ? ss * sv * sv : 0.f;
    }
    // fallback members (n > SLOTS): sc/x2 via LDS
    for (int mb = SLOTS + wv * 16; mb < n; mb += 64) {
#pragma unroll
        for (int t = 0; t < 2; ++t) {
            int  m   = mb + grp + 8 * t;
            bool act = (m < n);
            int  b   = act ? mlist[m] : 0;
            float ss = 0.f;
#pragma unroll
            for (int j = 0; j < 4; ++j) {
                float4 t4 = reps4[(size_t)b * 32 + 4 * q + j];
                ss += t4.x * t4.x + t4.y * t4.y + t4.z * t4.z + t4.w * t4.w;
            }
            ss = red8(ss);
            if (act && q == 0) {
                float nn = fmaxf(sqrtf(ss), EPSF);
                float sv = tanh_fast(nn) / nn;
                sc_l[m] = sv;
                x2_l[m] = ss * sv * sv;
            }
        }
    }

    // ---- transpose own 16 slots into dim-layout registers (wave-local reads)
    const float* xsf = (const float*)xs4;
    const int    lh  = lane >> 1, lb = (lane & 1) * 2;   // lane holds dims {2l, 2l+1}
    float2 xd[16];
#pragma unroll
    for (int k = 0; k < 16; ++k) {
        int m = wv * 16 + k;
        xd[k] = *(const float2*)&xsf[(m * 32 + (lh ^ (m & 7))) * 4 + lb];
    }

    // ---- init: per-wave partial Euclidean mean
    {
        float2 S; S.x = 0.f; S.y = 0.f;
#pragma unroll
        for (int k = 0; k < 16; ++k) { S.x += xd[k].x; S.y += xd[k].y; }
        for (int mb = SLOTS + wv * 16; mb < n; mb += 64) {
            for (int k = 0; k < 16; ++k) {
                int m = mb + k;
                if (m < n) {
                    float2 rv = reps2[(size_t)mlist[m] * 64 + lane];
                    float s = sc_l[m];
                    S.x += s * rv.x; S.y += s * rv.y;
                }
            }
        }
        *(float2*)&part[1][wv][2 * lane] = S;
    }
    __syncthreads();
    float2 muf; float mu2;
    {
        float2 T; T.x = 0.f; T.y = 0.f;
#pragma unroll
        for (int w2 = 0; w2 < 4; ++w2) {
            float2 pv = *(const float2*)&part[1][w2][2 * lane];
            T.x += pv.x; T.y += pv.y;
        }
        muf.x = T.x * inv_cnt; muf.y = T.y * inv_cnt;
        float m2  = wsum64(muf.x * muf.x + muf.y * muf.y);
        float nrm = fmaxf(sqrtf(m2), EPSF);
        float fac = fminf(1.0f, MAXNORM / nrm);
        muf.x *= fac; muf.y *= fac;
        mu2 = m2 * fac * fac;
        *(float2*)&mu_lds[2 * lane] = muf;
    }

    // ---- Karcher iterations: ONE barrier each; zero LDS row/weight reads
    for (int it = 0; it < ITERS; ++it) {
        const int buf = it & 1;
        const float4* mu4 = (const float4*)mu_lds;
        float4 ms[4];
#pragma unroll
        for (int j = 0; j < 4; ++j) ms[j] = mu4[4 * q + j];

        // phase 1: own 2 slots, register dots (all lanes keep w/cb)
        float wA, cbA, wB, cbB;
        {
            float d   = red8(dot16(rA, ms));
            float ca  = 1.0f - 2.0f * d + mu2;
            float cbv = 1.0f - x2A;
            float den = fmaxf(1.0f - 2.0f * d + x2A * mu2, EPSF);
            float iv  = 1.0f / den;
            bool  act = (mA < n);
            wA  = act ? ca * iv : 0.f;
            cbA = act ? cbv * iv : 0.f;
        }
        {
            float d   = red8(dot16(rB, ms));
            float ca  = 1.0f - 2.0f * d + mu2;
            float cbv = 1.0f - x2B;
            float den = fmaxf(1.0f - 2.0f * d + x2B * mu2, EPSF);
            float iv  = 1.0f / den;
            bool  act = (mB < n);
            wB  = act ? ca * iv : 0.f;
            cbB = act ? cbv * iv : 0.f;
        }
        for (int mb = SLOTS + wv * 16; mb < n; mb += 64) {
#pragma unroll
            for (int t = 0; t < 2; ++t) {
                int  m   = mb + grp + 8 * t;
                bool act = (m < n);
                int  b   = act ? mlist[m] : 0;
                float dd = 0.f;
#pragma unroll
                for (int j = 0; j < 4; ++j) {
                    float4 a = reps4[(size_t)b * 32 + 4 * q + j];
                    dd += a.x * ms[j].x + a.y * ms[j].y + a.z * ms[j].z + a.w * ms[j].w;
                }
                dd = red8(dd);
                if (act) {
                    float dp  = sc_l[m] * dd;
                    float x2v = x2_l[m];
                    float ca  = 1.0f - 2.0f * dp + mu2;
                    float cbv = 1.0f - x2v;
                    float den = fmaxf(1.0f - 2.0f * dp + x2v * mu2, EPSF);
                    float iv  = 1.0f / den;
                    if (q == 0) { w_l[m] = ca * iv; cb_l[m] = cbv * iv; }
                }
            }
        }

        // phase C: readlane weight broadcast + register FMAs
        float2 S2; S2.x = 0.f; S2.y = 0.f;
        float  scb = 0.f;
#pragma unroll
        for (int k = 0; k < 8; ++k) {
            float wk = rlane(wA, 8 * k);
            float ck = rlane(cbA, 8 * k);
            S2.x += wk * xd[k].x; S2.y += wk * xd[k].y;
            scb  += ck;
        }
#pragma unroll
        for (int k = 0; k < 8; ++k) {
            float wk = rlane(wB, 8 * k);
            float ck = rlane(cbB, 8 * k);
            S2.x += wk * xd[8 + k].x; S2.y += wk * xd[8 + k].y;
            scb  += ck;
        }
        for (int mb = SLOTS + wv * 16; mb < n; mb += 64) {
            for (int k = 0; k < 16; ++k) {
                int m = mb + k;
                if (m < n) {
                    float wvv = w_l[m] * sc_l[m];
                    scb += cb_l[m];
                    float2 rv = reps2[(size_t)mlist[m] * 64 + lane];
                    S2.x += wvv * rv.x; S2.y += wvv * rv.y;
                }
            }
        }
        *(float2*)&part[buf][wv][2 * lane] = S2;
        if (lane == 0) scbp[buf][wv] = scb;
        __syncthreads();                 // THE barrier

        // combine + mobius (redundant on every wave)
        float2 T; T.x = 0.f; T.y = 0.f;
#pragma unroll
        for (int w2 = 0; w2 < 4; ++w2) {
            float2 pv = *(const float2*)&part[buf][w2][2 * lane];
            T.x += pv.x; T.y += pv.y;
        }
        float scbt = scbp[buf][0] + scbp[buf][1] + scbp[buf][2] + scbp[buf][3];
        float scs  = scbt * inv_cnt;
        float2 md;
        md.x = T.x * inv_cnt - scs * muf.x;
        md.y = T.y * inv_cnt - scs * muf.y;

        float A0 = md.x * md.x + md.y * md.y;
        float A1 = muf.x * md.x + muf.y * md.y;
        wsum64_2(A0, A1);
        float ca  = 1.0f + 2.0f * A1 + A0;
        float cbv = 1.0f - mu2;
        float den = fmaxf(1.0f + 2.0f * A1 + mu2 * A0, EPSF);
        float iv  = 1.0f / den;
        float2 tv;
        tv.x = (ca * muf.x + cbv * md.x) * iv;
        tv.y = (ca * muf.y + cbv * md.y) * iv;
        float t2   = (ca * ca * mu2 + 2.0f * ca * cbv * A1 + cbv * cbv * A0) * iv * iv;
        float nrm2 = fmaxf(sqrtf(t2), EPSF);
        float fc   = fminf(1.0f, MAXNORM / nrm2);
        muf.x = tv.x * fc; muf.y = tv.y * fc;
        mu2   = t2 * fc * fc;
        *(float2*)&mu_lds[2 * lane] = muf;   // same values from all waves
    }

    // final project_to_ball + store (wave 0)
    {
        float nf = fmaxf(sqrtf(mu2), EPSF);
        float ff = fminf(1.0f, MAXNORM / nf);
        muf.x *= ff; muf.y *= ff;
        mu2 = mu2 * ff * ff;
    }
    if (wv == 0) {
        ((float2*)(mu_out + (size_t)p * D_N))[lane] = muf;
        if (lane == 0) mu2_out[p] = mu2;
    }
}

// ---------------------------------------------------------------------------
// Kernel 2: distances + Pearson, fused. 8 blocks x 1024 threads, thread=pair.
// ---------------------------------------------------------------------------
__global__ __launch_bounds__(1024) void distcorr_kernel(
        const float* __restrict__ mu,
        const float* __restrict__ mu2s,
        const int*   __restrict__ dT,
        double* __restrict__ gpart,
        int*    __restrict__ counter,
        float*  __restrict__ out) {
    __shared__ float  lmu[P_N * 129];
    __shared__ float  lmu2[P_N];
    __shared__ double sh[16][5];
    __shared__ int    s_last;

    const int tid = threadIdx.x;
#pragma unroll
    for (int e = 0; e < 16; ++e) {
        int idx = tid + e * 1024;
        lmu[(idx >> 7) * 129 + (idx & 127)] = mu[idx];
    }
    if (tid < P_N) lmu2[tid] = mu2s[tid];
    __syncthreads();

    int k = blockIdx.x * 1024 + tid;
    double p0 = 0.0, p1 = 0.0, p2 = 0.0, p3 = 0.0, p4 = 0.0;
    if (k < NPAIRS) {
        int i = (int)(127.5f - sqrtf(127.5f * 127.5f - 2.0f * (float)k));
        if (i < 0) i = 0;
        while ((i + 1) * (2 * P_N - i - 2) / 2 <= k) ++i;
        while (i * (2 * P_N - i - 1) / 2 > k) --i;
        int j = k - i * (2 * P_N - i - 1) / 2 + i + 1;

        const float* ra = &lmu[i * 129];
        const float* rb = &lmu[j * 129];
        float a0 = 0.f, a1 = 0.f, a2 = 0.f, a3 = 0.f;
#pragma unroll
        for (int d = 0; d < D_N; d += 4) {
            float f0 = ra[d]     - rb[d];
            float f1 = ra[d + 1] - rb[d + 1];
            float f2 = ra[d + 2] - rb[d + 2];
            float f3 = ra[d + 3] - rb[d + 3];
            a0 += f0 * f0; a1 += f1 * f1; a2 += f2 * f2; a3 += f3 * f3;
        }
        float d2 = (a0 + a1) + (a2 + a3);
        float ai = fmaxf(1.f - lmu2[i], EPSF);
        float aj = fmaxf(1.f - lmu2[j], EPSF);
        float z  = 1.f + 2.f * d2 / fmaxf(ai * aj, EPSF);
        z = fmaxf(z, 1.f + EPSF);
        float dist = __logf(z + sqrtf(z * z - 1.f));   // fast acosh
        double bb = (double)dist;
        double tt = (double)dT[k];
        p0 = bb; p1 = bb * bb; p2 = tt; p3 = tt * tt; p4 = bb * tt;
    }
    p0 = wred64d(p0); p1 = wred64d(p1); p2 = wred64d(p2);
    p3 = wred64d(p3); p4 = wred64d(p4);
    const int wid = tid >> 6, lane = tid & 63;
    if (lane == 0) {
        sh[wid][0] = p0; sh[wid][1] = p1; sh[wid][2] = p2;
        sh[wid][3] = p3; sh[wid][4] = p4;
    }
    __syncthreads();
    if (tid == 0) {
        double b0 = 0, b1 = 0, b2 = 0, b3 = 0, b4 = 0;
        for (int w = 0; w < 16; ++w) {
            b0 += sh[w][0]; b1 += sh[w][1]; b2 += sh[w][2];
            b3 += sh[w][3]; b4 += sh[w][4];
        }
        double* gp = gpart + (size_t)blockIdx.x * 5;
        gp[0] = b0; gp[1] = b1; gp[2] = b2; gp[3] = b3; gp[4] = b4;
        __threadfence();
        int old = atomicAdd(counter, 1);
        s_last = (old == (int)gridDim.x - 1) ? 1 : 0;
    }
    __syncthreads();
    if (!s_last) return;
    if (tid == 0) {
        __threadfence();
        double t0 = 0, t1 = 0, t2 = 0, t3 = 0, t4 = 0;
        for (int b = 0; b < 8; ++b) {
            t0 += gpart[b * 5 + 0]; t1 += gpart[b * 5 + 1]; t2 += gpart[b * 5 + 2];
            t3 += gpart[b * 5 + 3]; t4 += gpart[b * 5 + 4];
        }
        const double nn = (double)NPAIRS;
        double mb  = t0 / nn;
        double mt  = t2 / nn;
        double cov = t4 - nn * mb * mt;
        double vb  = t1 - nn * mb * mb;
        double vt  = t3 - nn * mt * mt;
        double corr = cov / sqrt(vb * vt);
        double res  = isnan(corr) ? 1.0 : (1.0 - corr);
        out[0] = (float)res;
    }
}

// ---------------------------------------------------------------------------
extern "C" void kernel_launch(void* const* d_in, const int* in_sizes, int n_in,
                              void* d_out, int out_size, void* d_ws, size_t ws_size,
                              hipStream_t stream) {
    const float* reps    = (const float*)d_in[0];
    const int*   targets = (const int*)d_in[1];
    const int*   dT      = (const int*)d_in[2];
    float* out = (float*)d_out;

    double* gpart   = (double*)d_ws;                          // 8*5 doubles
    int*    counter = (int*)((char*)d_ws + 320);              // 1 int
    float*  mu      = (float*)((char*)d_ws + 384);            // P*D floats
    float*  mu2s    = mu + (size_t)P_N * D_N;                 // P floats

    proto_kernel<<<P_N, 256, 0, stream>>>(reps, targets, mu, mu2s, counter);
    distcorr_kernel<<<8, 1024, 0, stream>>>(mu, mu2s, dT, gpart, counter, out);
}

// Round 11
// 26.091 us; speedup vs baseline: 1.2202x; 1.0748x over previous
//
#include <hip/hip_runtime.h>
#include <math.h>

#define EPSF    1e-6f
#define B_N     4096
#define P_N     128
#define D_N     128
#define NPAIRS  (P_N * (P_N - 1) / 2)   // 8128 = 32 * 254
#define ITERS   10
#define MAXNORM 0.99999f                 // (1 - 1e-5) / sqrt(c), c = 1
#define MCAP    512                      // max members per group handled
#define WCAP    128                      // per-wave member list capacity
#define SLOTS   64                       // staged slots (16 per wave, wave-owned)
#define DBLK    32                       // distcorr blocks
#define PPB     254                      // pairs per distcorr block

// ---------------------------------------------------------------------------
// DPP / lane helpers
// ---------------------------------------------------------------------------
template <int CTRL>
__device__ __forceinline__ float dppadd(float x) {
    float t = __int_as_float(__builtin_amdgcn_update_dpp(
        0, __float_as_int(x), CTRL, 0xf, 0xf, true));
    return x + t;
}
__device__ __forceinline__ float red8(float x) {       // sum over aligned 8 lanes
    x = dppadd<0xB1>(x);    // quad_perm xor 1
    x = dppadd<0x4E>(x);    // quad_perm xor 2
    x = dppadd<0x141>(x);   // row_half_mirror: xor 7
    return x;
}
__device__ __forceinline__ float wsum64(float x) {
    x = dppadd<0x111>(x); x = dppadd<0x112>(x); x = dppadd<0x114>(x);
    x = dppadd<0x118>(x); x = dppadd<0x142>(x); x = dppadd<0x143>(x);
    return __int_as_float(__builtin_amdgcn_readlane(__float_as_int(x), 63));
}
__device__ __forceinline__ void wsum64_2(float& a, float& b) {
#define DPP_STEP(ctrl) \
    a = dppadd<ctrl>(a); b = dppadd<ctrl>(b);
    DPP_STEP(0x111) DPP_STEP(0x112) DPP_STEP(0x114) DPP_STEP(0x118) DPP_STEP(0x142) DPP_STEP(0x143)
#undef DPP_STEP
    a = __int_as_float(__builtin_amdgcn_readlane(__float_as_int(a), 63));
    b = __int_as_float(__builtin_amdgcn_readlane(__float_as_int(b), 63));
}
__device__ __forceinline__ double wred64d(double v) {
    v += __shfl_xor(v, 1);  v += __shfl_xor(v, 2);  v += __shfl_xor(v, 4);
    v += __shfl_xor(v, 8);  v += __shfl_xor(v, 16); v += __shfl_xor(v, 32);
    return v;
}
__device__ __forceinline__ float rlane(float v, int l) {   // l must fold to const
    return __int_as_float(__builtin_amdgcn_readlane(__float_as_int(v), l));
}
__device__ __forceinline__ float dot16(const float4* r, const float4* m) {
    float d = 0.f;
#pragma unroll
    for (int j = 0; j < 4; ++j)
        d += r[j].x * m[j].x + r[j].y * m[j].y + r[j].z * m[j].z + r[j].w * m[j].w;
    return d;
}
__device__ __forceinline__ float tanh_fast(float x) {      // x >= 0
    float t = __expf(-2.0f * x);
    return (1.0f - t) / (1.0f + t);
}

// ---------------------------------------------------------------------------
// Kernel 1: per-group Karcher mean (identical to R10 — verified absmax 0).
// ---------------------------------------------------------------------------
__global__ __launch_bounds__(256) void proto_kernel(
        const float* __restrict__ reps,
        const int*   __restrict__ targets,
        float* __restrict__ mu_out,
        float* __restrict__ mu2_out,
        int*   __restrict__ counter) {
    __shared__ int    wtmp[4][WCAP];
    __shared__ int    wcnt[4];
    __shared__ int    woff[4];
    __shared__ int    mlist[MCAP];
    __shared__ int    s_n;
    __shared__ float4 xs4[SLOTS * 32];   // 32 KiB; row m, f4-col c at [m*32 + (c^(m&7))]
    __shared__ float  sc_l[MCAP];        // fallback slots only
    __shared__ float  x2_l[MCAP];
    __shared__ float  w_l[MCAP];
    __shared__ float  cb_l[MCAP];
    __shared__ float  mu_lds[D_N];
    __shared__ float  part[2][4][D_N];
    __shared__ float  scbp[2][4];

    const int p    = blockIdx.x;
    const int tid  = threadIdx.x;
    const int wv   = tid >> 6;
    const int lane = tid & 63;
    const int grp  = lane >> 3;
    const int q    = lane & 7;

    if (p == 0 && tid == 0) counter[0] = 0;

    // ---- membership scan
    {
        int tg[16];
#pragma unroll
        for (int r = 0; r < 16; ++r) tg[r] = targets[(wv << 10) + (r << 6) + lane];
        const unsigned long long lowmask = (1ULL << lane) - 1ULL;
        int cnt = 0;
#pragma unroll
        for (int r = 0; r < 16; ++r) {
            bool mm = (tg[r] == p);
            unsigned long long mk = __ballot(mm);
            if (mm) {
                int pos = cnt + __popcll(mk & lowmask);
                if (pos < WCAP) wtmp[wv][pos] = (wv << 10) + (r << 6) + lane;
            }
            cnt += __popcll(mk);
        }
        if (cnt > WCAP) cnt = WCAP;
        if (lane == 0) wcnt[wv] = cnt;
    }
    __syncthreads();
    if (tid == 0) {
        int c0 = wcnt[0], c1 = wcnt[1], c2 = wcnt[2], c3 = wcnt[3];
        woff[0] = 0; woff[1] = c0; woff[2] = c0 + c1; woff[3] = c0 + c1 + c2;
        int nn = c0 + c1 + c2 + c3;
        s_n = (nn > MCAP) ? MCAP : nn;
    }
    __syncthreads();
    {
        int base = woff[wv], cnt = wcnt[wv];
        for (int i = lane; i < cnt; i += 64) mlist[base + i] = wtmp[wv][i];
    }
    __syncthreads();

    const int   n       = s_n;
    const float inv_cnt = 1.0f / fmaxf((float)n, 1.0f);
    const float4* reps4 = (const float4*)reps;
    const float2* reps2 = (const float2*)reps;

    const int mA = wv * 16 + grp;
    const int mB = mA + 8;

    // ---- stage own slots (expmap fused); keep x2 in registers
    float4 rA[4], rB[4];
    float  x2A, x2B;
    {
        bool act = (mA < n);
        int  b   = act ? mlist[mA] : 0;
        float ss = 0.f;
#pragma unroll
        for (int j = 0; j < 4; ++j) {
            rA[j] = reps4[(size_t)b * 32 + 4 * q + j];
            ss += rA[j].x * rA[j].x + rA[j].y * rA[j].y + rA[j].z * rA[j].z + rA[j].w * rA[j].w;
        }
        ss = red8(ss);
        float nn = fmaxf(sqrtf(ss), EPSF);
        float sv = act ? (tanh_fast(nn) / nn) : 0.f;
#pragma unroll
        for (int j = 0; j < 4; ++j) {
            rA[j].x *= sv; rA[j].y *= sv; rA[j].z *= sv; rA[j].w *= sv;
            xs4[mA * 32 + ((4 * q + j) ^ (mA & 7))] = rA[j];
        }
        x2A = act ? ss * sv * sv : 0.f;
    }
    {
        bool act = (mB < n);
        int  b   = act ? mlist[mB] : 0;
        float ss = 0.f;
#pragma unroll
        for (int j = 0; j < 4; ++j) {
            rB[j] = reps4[(size_t)b * 32 + 4 * q + j];
            ss += rB[j].x * rB[j].x + rB[j].y * rB[j].y + rB[j].z * rB[j].z + rB[j].w * rB[j].w;
        }
        ss = red8(ss);
        float nn = fmaxf(sqrtf(ss), EPSF);
        float sv = act ? (tanh_fast(nn) / nn) : 0.f;
#pragma unroll
        for (int j = 0; j < 4; ++j) {
            rB[j].x *= sv; rB[j].y *= sv; rB[j].z *= sv; rB[j].w *= sv;
            xs4[mB * 32 + ((4 * q + j) ^ (mB & 7))] = rB[j];
        }
        x2B = act ? ss * sv * sv : 0.f;
    }
    // fallback members (n > SLOTS): sc/x2 via LDS
    for (int mb = SLOTS + wv * 16; mb < n; mb += 64) {
#pragma unroll
        for (int t = 0; t < 2; ++t) {
            int  m   = mb + grp + 8 * t;
            bool act = (m < n);
            int  b   = act ? mlist[m] : 0;
            float ss = 0.f;
#pragma unroll
            for (int j = 0; j < 4; ++j) {
                float4 t4 = reps4[(size_t)b * 32 + 4 * q + j];
                ss += t4.x * t4.x + t4.y * t4.y + t4.z * t4.z + t4.w * t4.w;
            }
            ss = red8(ss);
            if (act && q == 0) {
                float nn = fmaxf(sqrtf(ss), EPSF);
                float sv = tanh_fast(nn) / nn;
                sc_l[m] = sv;
                x2_l[m] = ss * sv * sv;
            }
        }
    }

    // ---- transpose own 16 slots into dim-layout registers (wave-local reads)
    const float* xsf = (const float*)xs4;
    const int    lh  = lane >> 1, lb = (lane & 1) * 2;   // lane holds dims {2l, 2l+1}
    float2 xd[16];
#pragma unroll
    for (int k = 0; k < 16; ++k) {
        int m = wv * 16 + k;
        xd[k] = *(const float2*)&xsf[(m * 32 + (lh ^ (m & 7))) * 4 + lb];
    }

    // ---- init: per-wave partial Euclidean mean
    {
        float2 S; S.x = 0.f; S.y = 0.f;
#pragma unroll
        for (int k = 0; k < 16; ++k) { S.x += xd[k].x; S.y += xd[k].y; }
        for (int mb = SLOTS + wv * 16; mb < n; mb += 64) {
            for (int k = 0; k < 16; ++k) {
                int m = mb + k;
                if (m < n) {
                    float2 rv = reps2[(size_t)mlist[m] * 64 + lane];
                    float s = sc_l[m];
                    S.x += s * rv.x; S.y += s * rv.y;
                }
            }
        }
        *(float2*)&part[1][wv][2 * lane] = S;
    }
    __syncthreads();
    float2 muf; float mu2;
    {
        float2 T; T.x = 0.f; T.y = 0.f;
#pragma unroll
        for (int w2 = 0; w2 < 4; ++w2) {
            float2 pv = *(const float2*)&part[1][w2][2 * lane];
            T.x += pv.x; T.y += pv.y;
        }
        muf.x = T.x * inv_cnt; muf.y = T.y * inv_cnt;
        float m2  = wsum64(muf.x * muf.x + muf.y * muf.y);
        float nrm = fmaxf(sqrtf(m2), EPSF);
        float fac = fminf(1.0f, MAXNORM / nrm);
        muf.x *= fac; muf.y *= fac;
        mu2 = m2 * fac * fac;
        *(float2*)&mu_lds[2 * lane] = muf;
    }

    // ---- Karcher iterations: ONE barrier each; zero LDS row/weight reads
    for (int it = 0; it < ITERS; ++it) {
        const int buf = it & 1;
        const float4* mu4 = (const float4*)mu_lds;
        float4 ms[4];
#pragma unroll
        for (int j = 0; j < 4; ++j) ms[j] = mu4[4 * q + j];

        float wA, cbA, wB, cbB;
        {
            float d   = red8(dot16(rA, ms));
            float ca  = 1.0f - 2.0f * d + mu2;
            float cbv = 1.0f - x2A;
            float den = fmaxf(1.0f - 2.0f * d + x2A * mu2, EPSF);
            float iv  = 1.0f / den;
            bool  act = (mA < n);
            wA  = act ? ca * iv : 0.f;
            cbA = act ? cbv * iv : 0.f;
        }
        {
            float d   = red8(dot16(rB, ms));
            float ca  = 1.0f - 2.0f * d + mu2;
            float cbv = 1.0f - x2B;
            float den = fmaxf(1.0f - 2.0f * d + x2B * mu2, EPSF);
            float iv  = 1.0f / den;
            bool  act = (mB < n);
            wB  = act ? ca * iv : 0.f;
            cbB = act ? cbv * iv : 0.f;
        }
        for (int mb = SLOTS + wv * 16; mb < n; mb += 64) {
#pragma unroll
            for (int t = 0; t < 2; ++t) {
                int  m   = mb + grp + 8 * t;
                bool act = (m < n);
                int  b   = act ? mlist[m] : 0;
                float dd = 0.f;
#pragma unroll
                for (int j = 0; j < 4; ++j) {
                    float4 a = reps4[(size_t)b * 32 + 4 * q + j];
                    dd += a.x * ms[j].x + a.y * ms[j].y + a.z * ms[j].z + a.w * ms[j].w;
                }
                dd = red8(dd);
                if (act) {
                    float dp  = sc_l[m] * dd;
                    float x2v = x2_l[m];
                    float ca  = 1.0f - 2.0f * dp + mu2;
                    float cbv = 1.0f - x2v;
                    float den = fmaxf(1.0f - 2.0f * dp + x2v * mu2, EPSF);
                    float iv  = 1.0f / den;
                    if (q == 0) { w_l[m] = ca * iv; cb_l[m] = cbv * iv; }
                }
            }
        }

        // phase C: readlane weight broadcast + register FMAs
        float2 S2; S2.x = 0.f; S2.y = 0.f;
        float  scb = 0.f;
#pragma unroll
        for (int k = 0; k < 8; ++k) {
            float wk = rlane(wA, 8 * k);
            float ck = rlane(cbA, 8 * k);
            S2.x += wk * xd[k].x; S2.y += wk * xd[k].y;
            scb  += ck;
        }
#pragma unroll
        for (int k = 0; k < 8; ++k) {
            float wk = rlane(wB, 8 * k);
            float ck = rlane(cbB, 8 * k);
            S2.x += wk * xd[8 + k].x; S2.y += wk * xd[8 + k].y;
            scb  += ck;
        }
        for (int mb = SLOTS + wv * 16; mb < n; mb += 64) {
            for (int k = 0; k < 16; ++k) {
                int m = mb + k;
                if (m < n) {
                    float wvv = w_l[m] * sc_l[m];
                    scb += cb_l[m];
                    float2 rv = reps2[(size_t)mlist[m] * 64 + lane];
                    S2.x += wvv * rv.x; S2.y += wvv * rv.y;
                }
            }
        }
        *(float2*)&part[buf][wv][2 * lane] = S2;
        if (lane == 0) scbp[buf][wv] = scb;
        __syncthreads();                 // THE barrier

        // combine + mobius (redundant on every wave)
        float2 T; T.x = 0.f; T.y = 0.f;
#pragma unroll
        for (int w2 = 0; w2 < 4; ++w2) {
            float2 pv = *(const float2*)&part[buf][w2][2 * lane];
            T.x += pv.x; T.y += pv.y;
        }
        float scbt = scbp[buf][0] + scbp[buf][1] + scbp[buf][2] + scbp[buf][3];
        float scs  = scbt * inv_cnt;
        float2 md;
        md.x = T.x * inv_cnt - scs * muf.x;
        md.y = T.y * inv_cnt - scs * muf.y;

        float A0 = md.x * md.x + md.y * md.y;
        float A1 = muf.x * md.x + muf.y * md.y;
        wsum64_2(A0, A1);
        float ca  = 1.0f + 2.0f * A1 + A0;
        float cbv = 1.0f - mu2;
        float den = fmaxf(1.0f + 2.0f * A1 + mu2 * A0, EPSF);
        float iv  = 1.0f / den;
        float2 tv;
        tv.x = (ca * muf.x + cbv * md.x) * iv;
        tv.y = (ca * muf.y + cbv * md.y) * iv;
        float t2   = (ca * ca * mu2 + 2.0f * ca * cbv * A1 + cbv * cbv * A0) * iv * iv;
        float nrm2 = fmaxf(sqrtf(t2), EPSF);
        float fc   = fminf(1.0f, MAXNORM / nrm2);
        muf.x = tv.x * fc; muf.y = tv.y * fc;
        mu2   = t2 * fc * fc;
        *(float2*)&mu_lds[2 * lane] = muf;   // same values from all waves
    }

    // final project_to_ball + store (wave 0)
    {
        float nf = fmaxf(sqrtf(mu2), EPSF);
        float ff = fminf(1.0f, MAXNORM / nf);
        muf.x *= ff; muf.y *= ff;
        mu2 = mu2 * ff * ff;
    }
    if (wv == 0) {
        ((float2*)(mu_out + (size_t)p * D_N))[lane] = muf;
        if (lane == 0) mu2_out[p] = mu2;
    }
}

// ---------------------------------------------------------------------------
// Kernel 2: distances + Pearson. 32 blocks x 256 threads, thread = pair,
// DIRECT global float4 reads of mu (L2/LLC-resident, no LDS staging).
// ---------------------------------------------------------------------------
__global__ __launch_bounds__(256) void distcorr_kernel(
        const float* __restrict__ mu,
        const float* __restrict__ mu2s,
        const int*   __restrict__ dT,
        double* __restrict__ gpart,
        int*    __restrict__ counter,
        float*  __restrict__ out) {
    __shared__ double sh[4][5];
    __shared__ int    s_last;

    const int tid  = threadIdx.x;
    const int wid  = tid >> 6;
    const int lane = tid & 63;
    const int k    = blockIdx.x * PPB + tid;     // valid iff tid < PPB

    double p0 = 0.0, p1 = 0.0, p2 = 0.0, p3 = 0.0, p4 = 0.0;
    if (tid < PPB) {
        int i = (int)(127.5f - sqrtf(127.5f * 127.5f - 2.0f * (float)k));
        if (i < 0) i = 0;
        while ((i + 1) * (2 * P_N - i - 2) / 2 <= k) ++i;
        while (i * (2 * P_N - i - 1) / 2 > k) --i;
        int j = k - i * (2 * P_N - i - 1) / 2 + i + 1;

        const float4* ra = (const float4*)(mu + (size_t)i * D_N);
        const float4* rb = (const float4*)(mu + (size_t)j * D_N);
        float a0 = 0.f, a1 = 0.f, a2 = 0.f, a3 = 0.f;
#pragma unroll
        for (int d = 0; d < 32; ++d) {
            float4 a = ra[d], b = rb[d];
            float f0 = a.x - b.x, f1 = a.y - b.y, f2 = a.z - b.z, f3 = a.w - b.w;
            a0 += f0 * f0; a1 += f1 * f1; a2 += f2 * f2; a3 += f3 * f3;
        }
        float d2 = (a0 + a1) + (a2 + a3);
        float ai = fmaxf(1.f - mu2s[i], EPSF);
        float aj = fmaxf(1.f - mu2s[j], EPSF);
        float z  = 1.f + 2.f * d2 / fmaxf(ai * aj, EPSF);
        z = fmaxf(z, 1.f + EPSF);
        float dist = __logf(z + sqrtf(z * z - 1.f));   // fast acosh
        double bb = (double)dist;
        double tt = (double)dT[k];
        p0 = bb; p1 = bb * bb; p2 = tt; p3 = tt * tt; p4 = bb * tt;
    }
    p0 = wred64d(p0); p1 = wred64d(p1); p2 = wred64d(p2);
    p3 = wred64d(p3); p4 = wred64d(p4);
    if (lane == 0) {
        sh[wid][0] = p0; sh[wid][1] = p1; sh[wid][2] = p2;
        sh[wid][3] = p3; sh[wid][4] = p4;
    }
    __syncthreads();
    if (tid == 0) {
        double b0 = 0, b1 = 0, b2 = 0, b3 = 0, b4 = 0;
#pragma unroll
        for (int w = 0; w < 4; ++w) {
            b0 += sh[w][0]; b1 += sh[w][1]; b2 += sh[w][2];
            b3 += sh[w][3]; b4 += sh[w][4];
        }
        double* gp = gpart + (size_t)blockIdx.x * 5;
        gp[0] = b0; gp[1] = b1; gp[2] = b2; gp[3] = b3; gp[4] = b4;
        __threadfence();
        int old = atomicAdd(counter, 1);
        s_last = (old == (int)gridDim.x - 1) ? 1 : 0;
    }
    __syncthreads();
    if (!s_last) return;
    __threadfence();

    // last block: lane-parallel final reduce of 32 x 5 partials
    if (tid < 64) {
        double q0 = 0, q1 = 0, q2 = 0, q3 = 0, q4 = 0;
        if (lane < DBLK) {
            const double* gp = gpart + (size_t)lane * 5;
            q0 = gp[0]; q1 = gp[1]; q2 = gp[2]; q3 = gp[3]; q4 = gp[4];
        }
        q0 = wred64d(q0); q1 = wred64d(q1); q2 = wred64d(q2);
        q3 = wred64d(q3); q4 = wred64d(q4);
        if (tid == 0) {
            const double nn = (double)NPAIRS;
            double mb  = q0 / nn;
            double mt  = q2 / nn;
            double cov = q4 - nn * mb * mt;
            double vb  = q1 - nn * mb * mb;
            double vt  = q3 - nn * mt * mt;
            double corr = cov / sqrt(vb * vt);
            double res  = isnan(corr) ? 1.0 : (1.0 - corr);
            out[0] = (float)res;
        }
    }
}

// ---------------------------------------------------------------------------
extern "C" void kernel_launch(void* const* d_in, const int* in_sizes, int n_in,
                              void* d_out, int out_size, void* d_ws, size_t ws_size,
                              hipStream_t stream) {
    const float* reps    = (const float*)d_in[0];
    const int*   targets = (const int*)d_in[1];
    const int*   dT      = (const int*)d_in[2];
    float* out = (float*)d_out;

    double* gpart   = (double*)d_ws;                          // 32*5 doubles = 1280 B
    int*    counter = (int*)((char*)d_ws + 1280);             // 1 int
    float*  mu      = (float*)((char*)d_ws + 1536);           // P*D floats
    float*  mu2s    = mu + (size_t)P_N * D_N;                 // P floats

    proto_kernel<<<P_N, 256, 0, stream>>>(reps, targets, mu, mu2s, counter);
    distcorr_kernel<<<DBLK, 256, 0, stream>>>(mu, mu2s, dT, gpart, counter, out);
}

// Round 12
// 26.032 us; speedup vs baseline: 1.2229x; 1.0023x over previous
//
#include <hip/hip_runtime.h>
#include <math.h>

#define EPSF    1e-6f
#define B_N     4096
#define P_N     128
#define D_N     128
#define NPAIRS  (P_N * (P_N - 1) / 2)   // 8128 = 32 * 254
#define ITERS   10
#define MAXNORM 0.99999f                 // (1 - 1e-5) / sqrt(c), c = 1
#define MCAP    512                      // max members per group handled
#define WCAP    128                      // per-wave member list capacity
#define SLOTS   64                       // staged slots (16 per wave, wave-owned)
#define DBLK    32                       // distcorr blocks
#define PPB     254                      // pairs per distcorr block

// ---------------------------------------------------------------------------
// DPP / lane helpers
// ---------------------------------------------------------------------------
template <int CTRL>
__device__ __forceinline__ float dppadd(float x) {
    float t = __int_as_float(__builtin_amdgcn_update_dpp(
        0, __float_as_int(x), CTRL, 0xf, 0xf, true));
    return x + t;
}
__device__ __forceinline__ float red8(float x) {       // sum over aligned 8 lanes
    x = dppadd<0xB1>(x);    // quad_perm xor 1
    x = dppadd<0x4E>(x);    // quad_perm xor 2
    x = dppadd<0x141>(x);   // row_half_mirror: xor 7
    return x;
}
__device__ __forceinline__ float wsum64(float x) {
    x = dppadd<0x111>(x); x = dppadd<0x112>(x); x = dppadd<0x114>(x);
    x = dppadd<0x118>(x); x = dppadd<0x142>(x); x = dppadd<0x143>(x);
    return __int_as_float(__builtin_amdgcn_readlane(__float_as_int(x), 63));
}
__device__ __forceinline__ void wsum64_2(float& a, float& b) {
#define DPP_STEP(ctrl) \
    a = dppadd<ctrl>(a); b = dppadd<ctrl>(b);
    DPP_STEP(0x111) DPP_STEP(0x112) DPP_STEP(0x114) DPP_STEP(0x118) DPP_STEP(0x142) DPP_STEP(0x143)
#undef DPP_STEP
    a = __int_as_float(__builtin_amdgcn_readlane(__float_as_int(a), 63));
    b = __int_as_float(__builtin_amdgcn_readlane(__float_as_int(b), 63));
}
__device__ __forceinline__ double wred64d(double v) {
    v += __shfl_xor(v, 1);  v += __shfl_xor(v, 2);  v += __shfl_xor(v, 4);
    v += __shfl_xor(v, 8);  v += __shfl_xor(v, 16); v += __shfl_xor(v, 32);
    return v;
}
__device__ __forceinline__ float rlane(float v, int l) {   // l must fold to const
    return __int_as_float(__builtin_amdgcn_readlane(__float_as_int(v), l));
}
__device__ __forceinline__ float dot16(const float4* r, const float4* m) {
    float d = 0.f;
#pragma unroll
    for (int j = 0; j < 4; ++j)
        d += r[j].x * m[j].x + r[j].y * m[j].y + r[j].z * m[j].z + r[j].w * m[j].w;
    return d;
}
__device__ __forceinline__ float tanh_fast(float x) {      // x >= 0
    float t = __expf(-2.0f * x);
    return (1.0f - t) / (1.0f + t);
}

// ---------------------------------------------------------------------------
// Kernel 1: per-group Karcher mean. R10/R11 structure; setup trimmed to
// 2 barriers (woff/s_n computed redundantly per thread).
// ---------------------------------------------------------------------------
__global__ __launch_bounds__(256) void proto_kernel(
        const float* __restrict__ reps,
        const int*   __restrict__ targets,
        float* __restrict__ mu_out,
        float* __restrict__ mu2_out,
        int*   __restrict__ counter) {
    __shared__ int    wtmp[4][WCAP];
    __shared__ int    wcnt[4];
    __shared__ int    mlist[MCAP];
    __shared__ float4 xs4[SLOTS * 32];   // 32 KiB; row m, f4-col c at [m*32 + (c^(m&7))]
    __shared__ float  sc_l[MCAP];        // fallback slots only
    __shared__ float  x2_l[MCAP];
    __shared__ float  w_l[MCAP];
    __shared__ float  cb_l[MCAP];
    __shared__ float  mu_lds[D_N];
    __shared__ float  part[2][4][D_N];
    __shared__ float  scbp[2][4];

    const int p    = blockIdx.x;
    const int tid  = threadIdx.x;
    const int wv   = tid >> 6;
    const int lane = tid & 63;
    const int grp  = lane >> 3;
    const int q    = lane & 7;

    if (p == 0 && tid == 0) counter[0] = 0;

    // ---- membership scan (loads hoisted)
    {
        int tg[16];
#pragma unroll
        for (int r = 0; r < 16; ++r) tg[r] = targets[(wv << 10) + (r << 6) + lane];
        const unsigned long long lowmask = (1ULL << lane) - 1ULL;
        int cnt = 0;
#pragma unroll
        for (int r = 0; r < 16; ++r) {
            bool mm = (tg[r] == p);
            unsigned long long mk = __ballot(mm);
            if (mm) {
                int pos = cnt + __popcll(mk & lowmask);
                if (pos < WCAP) wtmp[wv][pos] = (wv << 10) + (r << 6) + lane;
            }
            cnt += __popcll(mk);
        }
        if (cnt > WCAP) cnt = WCAP;
        if (lane == 0) wcnt[wv] = cnt;
    }
    __syncthreads();                      // barrier 1: wcnt visible

    // redundant per-thread offsets (no tid0 section, no extra barrier)
    const int c0 = wcnt[0], c1 = wcnt[1], c2 = wcnt[2], c3 = wcnt[3];
    int wofv[4]; wofv[0] = 0; wofv[1] = c0; wofv[2] = c0 + c1; wofv[3] = c0 + c1 + c2;
    int ntot = c0 + c1 + c2 + c3;
    const int n = (ntot > MCAP) ? MCAP : ntot;
    {
        int base = wofv[wv], cnt = wcnt[wv];
        for (int i = lane; i < cnt; i += 64) mlist[base + i] = wtmp[wv][i];
    }
    __syncthreads();                      // barrier 2: mlist complete

    const float inv_cnt = 1.0f / fmaxf((float)n, 1.0f);
    const float4* reps4 = (const float4*)reps;
    const float2* reps2 = (const float2*)reps;

    const int mA = wv * 16 + grp;
    const int mB = mA + 8;

    // ---- stage own slots (expmap fused); keep x2 in registers
    float4 rA[4], rB[4];
    float  x2A, x2B;
    {
        bool act = (mA < n);
        int  b   = act ? mlist[mA] : 0;
        float ss = 0.f;
#pragma unroll
        for (int j = 0; j < 4; ++j) {
            rA[j] = reps4[(size_t)b * 32 + 4 * q + j];
            ss += rA[j].x * rA[j].x + rA[j].y * rA[j].y + rA[j].z * rA[j].z + rA[j].w * rA[j].w;
        }
        ss = red8(ss);
        float nn = fmaxf(sqrtf(ss), EPSF);
        float sv = act ? (tanh_fast(nn) / nn) : 0.f;
#pragma unroll
        for (int j = 0; j < 4; ++j) {
            rA[j].x *= sv; rA[j].y *= sv; rA[j].z *= sv; rA[j].w *= sv;
            xs4[mA * 32 + ((4 * q + j) ^ (mA & 7))] = rA[j];
        }
        x2A = act ? ss * sv * sv : 0.f;
    }
    {
        bool act = (mB < n);
        int  b   = act ? mlist[mB] : 0;
        float ss = 0.f;
#pragma unroll
        for (int j = 0; j < 4; ++j) {
            rB[j] = reps4[(size_t)b * 32 + 4 * q + j];
            ss += rB[j].x * rB[j].x + rB[j].y * rB[j].y + rB[j].z * rB[j].z + rB[j].w * rB[j].w;
        }
        ss = red8(ss);
        float nn = fmaxf(sqrtf(ss), EPSF);
        float sv = act ? (tanh_fast(nn) / nn) : 0.f;
#pragma unroll
        for (int j = 0; j < 4; ++j) {
            rB[j].x *= sv; rB[j].y *= sv; rB[j].z *= sv; rB[j].w *= sv;
            xs4[mB * 32 + ((4 * q + j) ^ (mB & 7))] = rB[j];
        }
        x2B = act ? ss * sv * sv : 0.f;
    }
    // fallback members (n > SLOTS): sc/x2 via LDS
    for (int mb = SLOTS + wv * 16; mb < n; mb += 64) {
#pragma unroll
        for (int t = 0; t < 2; ++t) {
            int  m   = mb + grp + 8 * t;
            bool act = (m < n);
            int  b   = act ? mlist[m] : 0;
            float ss = 0.f;
#pragma unroll
            for (int j = 0; j < 4; ++j) {
                float4 t4 = reps4[(size_t)b * 32 + 4 * q + j];
                ss += t4.x * t4.x + t4.y * t4.y + t4.z * t4.z + t4.w * t4.w;
            }
            ss = red8(ss);
            if (act && q == 0) {
                float nn = fmaxf(sqrtf(ss), EPSF);
                float sv = tanh_fast(nn) / nn;
                sc_l[m] = sv;
                x2_l[m] = ss * sv * sv;
            }
        }
    }

    // ---- transpose own 16 slots into dim-layout registers (wave-local reads)
    const float* xsf = (const float*)xs4;
    const int    lh  = lane >> 1, lb = (lane & 1) * 2;   // lane holds dims {2l, 2l+1}
    float2 xd[16];
#pragma unroll
    for (int k = 0; k < 16; ++k) {
        int m = wv * 16 + k;
        xd[k] = *(const float2*)&xsf[(m * 32 + (lh ^ (m & 7))) * 4 + lb];
    }

    // ---- init: per-wave partial Euclidean mean
    {
        float2 S; S.x = 0.f; S.y = 0.f;
#pragma unroll
        for (int k = 0; k < 16; ++k) { S.x += xd[k].x; S.y += xd[k].y; }
        for (int mb = SLOTS + wv * 16; mb < n; mb += 64) {
            for (int k = 0; k < 16; ++k) {
                int m = mb + k;
                if (m < n) {
                    float2 rv = reps2[(size_t)mlist[m] * 64 + lane];
                    float s = sc_l[m];
                    S.x += s * rv.x; S.y += s * rv.y;
                }
            }
        }
        *(float2*)&part[1][wv][2 * lane] = S;
    }
    __syncthreads();
    float2 muf; float mu2;
    {
        float2 T; T.x = 0.f; T.y = 0.f;
#pragma unroll
        for (int w2 = 0; w2 < 4; ++w2) {
            float2 pv = *(const float2*)&part[1][w2][2 * lane];
            T.x += pv.x; T.y += pv.y;
        }
        muf.x = T.x * inv_cnt; muf.y = T.y * inv_cnt;
        float m2  = wsum64(muf.x * muf.x + muf.y * muf.y);
        float nrm = fmaxf(sqrtf(m2), EPSF);
        float fac = fminf(1.0f, MAXNORM / nrm);
        muf.x *= fac; muf.y *= fac;
        mu2 = m2 * fac * fac;
        *(float2*)&mu_lds[2 * lane] = muf;
    }

    // ---- Karcher iterations: ONE barrier each
    for (int it = 0; it < ITERS; ++it) {
        const int buf = it & 1;
        const float4* mu4 = (const float4*)mu_lds;
        float4 ms[4];
#pragma unroll
        for (int j = 0; j < 4; ++j) ms[j] = mu4[4 * q + j];

        float wA, cbA, wB, cbB;
        {
            float d   = red8(dot16(rA, ms));
            float ca  = 1.0f - 2.0f * d + mu2;
            float cbv = 1.0f - x2A;
            float den = fmaxf(1.0f - 2.0f * d + x2A * mu2, EPSF);
            float iv  = 1.0f / den;
            bool  act = (mA < n);
            wA  = act ? ca * iv : 0.f;
            cbA = act ? cbv * iv : 0.f;
        }
        {
            float d   = red8(dot16(rB, ms));
            float ca  = 1.0f - 2.0f * d + mu2;
            float cbv = 1.0f - x2B;
            float den = fmaxf(1.0f - 2.0f * d + x2B * mu2, EPSF);
            float iv  = 1.0f / den;
            bool  act = (mB < n);
            wB  = act ? ca * iv : 0.f;
            cbB = act ? cbv * iv : 0.f;
        }
        for (int mb = SLOTS + wv * 16; mb < n; mb += 64) {
#pragma unroll
            for (int t = 0; t < 2; ++t) {
                int  m   = mb + grp + 8 * t;
                bool act = (m < n);
                int  b   = act ? mlist[m] : 0;
                float dd = 0.f;
#pragma unroll
                for (int j = 0; j < 4; ++j) {
                    float4 a = reps4[(size_t)b * 32 + 4 * q + j];
                    dd += a.x * ms[j].x + a.y * ms[j].y + a.z * ms[j].z + a.w * ms[j].w;
                }
                dd = red8(dd);
                if (act) {
                    float dp  = sc_l[m] * dd;
                    float x2v = x2_l[m];
                    float ca  = 1.0f - 2.0f * dp + mu2;
                    float cbv = 1.0f - x2v;
                    float den = fmaxf(1.0f - 2.0f * dp + x2v * mu2, EPSF);
                    float iv  = 1.0f / den;
                    if (q == 0) { w_l[m] = ca * iv; cb_l[m] = cbv * iv; }
                }
            }
        }

        // phase C: readlane weight broadcast + register FMAs
        float2 S2; S2.x = 0.f; S2.y = 0.f;
        float  scb = 0.f;
#pragma unroll
        for (int k = 0; k < 8; ++k) {
            float wk = rlane(wA, 8 * k);
            float ck = rlane(cbA, 8 * k);
            S2.x += wk * xd[k].x; S2.y += wk * xd[k].y;
            scb  += ck;
        }
#pragma unroll
        for (int k = 0; k < 8; ++k) {
            float wk = rlane(wB, 8 * k);
            float ck = rlane(cbB, 8 * k);
            S2.x += wk * xd[8 + k].x; S2.y += wk * xd[8 + k].y;
            scb  += ck;
        }
        for (int mb = SLOTS + wv * 16; mb < n; mb += 64) {
            for (int k = 0; k < 16; ++k) {
                int m = mb + k;
                if (m < n) {
                    float wvv = w_l[m] * sc_l[m];
                    scb += cb_l[m];
                    float2 rv = reps2[(size_t)mlist[m] * 64 + lane];
                    S2.x += wvv * rv.x; S2.y += wvv * rv.y;
                }
            }
        }
        *(float2*)&part[buf][wv][2 * lane] = S2;
        if (lane == 0) scbp[buf][wv] = scb;
        __syncthreads();                 // THE barrier

        // combine + mobius (redundant on every wave)
        float2 T; T.x = 0.f; T.y = 0.f;
#pragma unroll
        for (int w2 = 0; w2 < 4; ++w2) {
            float2 pv = *(const float2*)&part[buf][w2][2 * lane];
            T.x += pv.x; T.y += pv.y;
        }
        float scbt = scbp[buf][0] + scbp[buf][1] + scbp[buf][2] + scbp[buf][3];
        float scs  = scbt * inv_cnt;
        float2 md;
        md.x = T.x * inv_cnt - scs * muf.x;
        md.y = T.y * inv_cnt - scs * muf.y;

        float A0 = md.x * md.x + md.y * md.y;
        float A1 = muf.x * md.x + muf.y * md.y;
        wsum64_2(A0, A1);
        float ca  = 1.0f + 2.0f * A1 + A0;
        float cbv = 1.0f - mu2;
        float den = fmaxf(1.0f + 2.0f * A1 + mu2 * A0, EPSF);
        float iv  = 1.0f / den;
        float2 tv;
        tv.x = (ca * muf.x + cbv * md.x) * iv;
        tv.y = (ca * muf.y + cbv * md.y) * iv;
        float t2   = (ca * ca * mu2 + 2.0f * ca * cbv * A1 + cbv * cbv * A0) * iv * iv;
        float nrm2 = fmaxf(sqrtf(t2), EPSF);
        float fc   = fminf(1.0f, MAXNORM / nrm2);
        muf.x = tv.x * fc; muf.y = tv.y * fc;
        mu2   = t2 * fc * fc;
        *(float2*)&mu_lds[2 * lane] = muf;   // same values from all waves
    }

    // final project_to_ball + store (waves 0 and 1 in parallel)
    {
        float nf = fmaxf(sqrtf(mu2), EPSF);
        float ff = fminf(1.0f, MAXNORM / nf);
        muf.x *= ff; muf.y *= ff;
        mu2 = mu2 * ff * ff;
    }
    if (wv == 0) {
        ((float2*)(mu_out + (size_t)p * D_N))[lane] = muf;
    } else if (wv == 1 && lane == 0) {
        mu2_out[p] = mu2;
    }
}

// ---------------------------------------------------------------------------
// Kernel 2: distances + Pearson. 32 blocks x 256 threads, thread = pair,
// direct global float4 reads of mu (no LDS staging); dT prefetched early.
// ---------------------------------------------------------------------------
__global__ __launch_bounds__(256) void distcorr_kernel(
        const float* __restrict__ mu,
        const float* __restrict__ mu2s,
        const int*   __restrict__ dT,
        double* __restrict__ gpart,
        int*    __restrict__ counter,
        float*  __restrict__ out) {
    __shared__ double sh[4][5];
    __shared__ int    s_last;

    const int tid  = threadIdx.x;
    const int wid  = tid >> 6;
    const int lane = tid & 63;
    const int k    = blockIdx.x * PPB + tid;     // valid iff tid < PPB

    double p0 = 0.0, p1 = 0.0, p2 = 0.0, p3 = 0.0, p4 = 0.0;
    if (tid < PPB) {
        int tval = dT[k];                        // prefetch: overlaps mu loads

        int i = (int)(127.5f - sqrtf(127.5f * 127.5f - 2.0f * (float)k));
        if (i < 0) i = 0;
        while ((i + 1) * (2 * P_N - i - 2) / 2 <= k) ++i;
        while (i * (2 * P_N - i - 1) / 2 > k) --i;
        int j = k - i * (2 * P_N - i - 1) / 2 + i + 1;

        const float4* ra = (const float4*)(mu + (size_t)i * D_N);
        const float4* rb = (const float4*)(mu + (size_t)j * D_N);
        float a0 = 0.f, a1 = 0.f, a2 = 0.f, a3 = 0.f;
#pragma unroll
        for (int d = 0; d < 32; ++d) {
            float4 a = ra[d], b = rb[d];
            float f0 = a.x - b.x, f1 = a.y - b.y, f2 = a.z - b.z, f3 = a.w - b.w;
            a0 += f0 * f0; a1 += f1 * f1; a2 += f2 * f2; a3 += f3 * f3;
        }
        float d2 = (a0 + a1) + (a2 + a3);
        float ai = fmaxf(1.f - mu2s[i], EPSF);
        float aj = fmaxf(1.f - mu2s[j], EPSF);
        float z  = 1.f + 2.f * d2 / fmaxf(ai * aj, EPSF);
        z = fmaxf(z, 1.f + EPSF);
        float dist = __logf(z + sqrtf(z * z - 1.f));   // fast acosh
        double bb = (double)dist;
        double tt = (double)tval;
        p0 = bb; p1 = bb * bb; p2 = tt; p3 = tt * tt; p4 = bb * tt;
    }
    p0 = wred64d(p0); p1 = wred64d(p1); p2 = wred64d(p2);
    p3 = wred64d(p3); p4 = wred64d(p4);
    if (lane == 0) {
        sh[wid][0] = p0; sh[wid][1] = p1; sh[wid][2] = p2;
        sh[wid][3] = p3; sh[wid][4] = p4;
    }
    __syncthreads();
    if (tid == 0) {
        double b0 = 0, b1 = 0, b2 = 0, b3 = 0, b4 = 0;
#pragma unroll
        for (int w = 0; w < 4; ++w) {
            b0 += sh[w][0]; b1 += sh[w][1]; b2 += sh[w][2];
            b3 += sh[w][3]; b4 += sh[w][4];
        }
        double* gp = gpart + (size_t)blockIdx.x * 5;
        gp[0] = b0; gp[1] = b1; gp[2] = b2; gp[3] = b3; gp[4] = b4;
        __threadfence();
        int old = atomicAdd(counter, 1);
        s_last = (old == (int)gridDim.x - 1) ? 1 : 0;
    }
    __syncthreads();
    if (!s_last) return;
    __threadfence();

    // last block: lane-parallel final reduce of 32 x 5 partials
    if (tid < 64) {
        double q0 = 0, q1 = 0, q2 = 0, q3 = 0, q4 = 0;
        if (lane < DBLK) {
            const double* gp = gpart + (size_t)lane * 5;
            q0 = gp[0]; q1 = gp[1]; q2 = gp[2]; q3 = gp[3]; q4 = gp[4];
        }
        q0 = wred64d(q0); q1 = wred64d(q1); q2 = wred64d(q2);
        q3 = wred64d(q3); q4 = wred64d(q4);
        if (tid == 0) {
            const double nn = (double)NPAIRS;
            double mb  = q0 / nn;
            double mt  = q2 / nn;
            double cov = q4 - nn * mb * mt;
            double vb  = q1 - nn * mb * mb;
            double vt  = q3 - nn * mt * mt;
            double corr = cov / sqrt(vb * vt);
            double res  = isnan(corr) ? 1.0 : (1.0 - corr);
            out[0] = (float)res;
        }
    }
}

// ---------------------------------------------------------------------------
extern "C" void kernel_launch(void* const* d_in, const int* in_sizes, int n_in,
                              void* d_out, int out_size, void* d_ws, size_t ws_size,
                              hipStream_t stream) {
    const float* reps    = (const float*)d_in[0];
    const int*   targets = (const int*)d_in[1];
    const int*   dT      = (const int*)d_in[2];
    float* out = (float*)d_out;

    double* gpart   = (double*)d_ws;                          // 32*5 doubles = 1280 B
    int*    counter = (int*)((char*)d_ws + 1280);             // 1 int
    float*  mu      = (float*)((char*)d_ws + 1536);           // P*D floats
    float*  mu2s    = mu + (size_t)P_N * D_N;                 // P floats

    proto_kernel<<<P_N, 256, 0, stream>>>(reps, targets, mu, mu2s, counter);
    distcorr_kernel<<<DBLK, 256, 0, stream>>>(mu, mu2s, dT, gpart, counter, out);
}